// Round 9
// baseline (1380.310 us; speedup 1.0000x reference)
//
#include <hip/hip_runtime.h>
#include <hip/hip_bf16.h>
#include <stdint.h>

// B=8192, D_IN=1024, D_HID=4096, D_OUT=1024, E=8
#define BB 8192
#define DIN 1024
#define DHID 4096
#define DOUT 1024
#define NEXP 8
#define GH_N 2048  // D_HID/2

typedef __attribute__((ext_vector_type(8))) __bf16 bf16x8;
typedef __attribute__((ext_vector_type(4))) float f32x4;

__device__ inline unsigned short f2bf(float f) {
  unsigned u = __builtin_bit_cast(unsigned, f);
  u = (u + 0x7FFFu + ((u >> 16) & 1u)) >> 16;
  return (unsigned short)u;
}
__device__ inline float b2f(unsigned short s) {
  return __builtin_bit_cast(float, (unsigned)s << 16);
}

// ---------------- elementwise f32 -> bf16 ----------------
__global__ void cvt_f32_bf16(const float* __restrict__ in,
                             unsigned short* __restrict__ out, int n4) {
  int i = blockIdx.x * blockDim.x + threadIdx.x;
  if (i >= n4) return;
  float4 v = ((const float4*)in)[i];
  ushort4 o;
  o.x = f2bf(v.x); o.y = f2bf(v.y); o.z = f2bf(v.z); o.w = f2bf(v.w);
  ((ushort4*)out)[i] = o;
}

// ------------- transpose + convert, 64x64 tile: in[R][C] f32 -> out[C][R] bf16
__device__ inline void tr_tile64(const float* __restrict__ in,
                                 unsigned short* __restrict__ out, int R, int C,
                                 int bx, int by) {
  __shared__ float tile[64][65];
  const int c0 = bx * 64, r0 = by * 64;
  const int tx = threadIdx.x & 63, ty = threadIdx.x >> 6;  // ty 0..3
#pragma unroll
  for (int i = 0; i < 16; ++i) {
    int r = i * 4 + ty;
    tile[r][tx] = in[(size_t)(r0 + r) * C + c0 + tx];
  }
  __syncthreads();
#pragma unroll
  for (int i = 0; i < 16; ++i) {
    int r = i * 4 + ty;
    out[(size_t)(c0 + r) * R + r0 + tx] = f2bf(tile[tx][r]);
  }
}

__global__ void transpose_cvt64(const float* __restrict__ in,
                                unsigned short* __restrict__ out, int R, int C) {
  tr_tile64(in, out, R, C, blockIdx.x, blockIdx.y);
}

// fused per-expert: W1 [1024][4096]->w1T[4096][1024], W2 [4096][1024]->w2T[1024][4096]
__global__ void transpose_cvt2(const float* __restrict__ w1,
                               unsigned short* __restrict__ w1T,
                               const float* __restrict__ w2,
                               unsigned short* __restrict__ w2T) {
  int b = blockIdx.x;
  if (b < 1024) {
    tr_tile64(w1, w1T, DIN, DHID, b & 63, b >> 6);
  } else {
    b -= 1024;
    tr_tile64(w2, w2T, DHID, DOUT, b & 15, b >> 4);
  }
}

// ---------------- async global->LDS 16B ----------------
__device__ inline void gload16(const void* g, void* l) {
  __builtin_amdgcn_global_load_lds(
      (const __attribute__((address_space(1))) void*)g,
      (__attribute__((address_space(3))) void*)l, 16, 0, 0);
}

template <int N>
__device__ inline void waitv() {
  if constexpr (N == 0) asm volatile("s_waitcnt vmcnt(0)" ::: "memory");
  else if constexpr (N == 3) asm volatile("s_waitcnt vmcnt(3)" ::: "memory");
  else if constexpr (N == 4) asm volatile("s_waitcnt vmcnt(4)" ::: "memory");
  else asm volatile("s_waitcnt vmcnt(0)" ::: "memory");
}
__device__ inline bf16x8 ldr(const char* p) { return *(const bf16x8*)p; }

// ---------------- gemmK: minimal-barrier GEMM (AITER-style loop) -----------
// C = A[8192,K]*Bt[N,K]^T. BN=256, BK=32, 8 waves (2M x 4N), 3-buffer LDS
// ring, stage 2 tiles ahead. Per K-tile: ds_reads | stage(T+2) | MFMA
// (compiler-scheduled lgkmcnt) | vmcnt(U) | s_barrier.  ONE barrier, ONE
// shallow vmcnt per tile; never vmcnt(0) mid-loop.
// Correctness: buf(T+2)%3 last read in tile T-1 (before its end barrier);
// each wave's vmcnt(U) at end of T retires its own T-1 stages (buf T+1 data),
// so post-barrier buf T+1 is complete for all waves. Drift < 1 tile.
// EPI 0: outb = bf16(relu(acc + bias[col]))
// EPI 1: outf (+)= gates[row*8+eidx]*(acc + bias[col])   (non-atomic RMW)
template <int BM, int EPI>
__global__ __launch_bounds__(512)
void gemmK(const unsigned short* __restrict__ A, int lda,
           const unsigned short* __restrict__ Bt, int ldb,
           int N, int K,
           const float* __restrict__ bias,
           unsigned short* __restrict__ outb,
           float* __restrict__ outf,
           const float* __restrict__ gates, int eidx, int accum, int nb) {
  constexpr int ABYTES = BM * 64;       // A bytes per slot (BK=32)
  constexpr int BBYTES = 16384;         // 256*64
  constexpr int SLOT = ABYTES + BBYTES;
  constexpr int AUN = BM / 128;         // A stage units: 2 or 1
  constexpr int U = AUN + 2;            // units per tile: 4 or 3
  constexpr int RM = BM / 32;           // A frags per wave: 8 or 4
  __shared__ char lds[3 * SLOT];

  const int t = threadIdx.x;
  const int lane = t & 63;
  const int wid = t >> 6;
  const int wm = wid >> 2;  // 0..1
  const int wn = wid & 3;   // 0..3
  const int l15 = lane & 15, lg = lane >> 4;

  // bijective XCD swizzle (nb % 8 == 0)
  const int local = blockIdx.x;
  const int swz = (local & 7) * (nb >> 3) + (local >> 3);
  const int nbn = N >> 8;
  const int bn = swz % nbn, bm = swz / nbn;
  const int m0 = bm * BM, n0 = bn * 256;

  // stage mapping: per 8KB unit, thread t -> (row = t>>2, phys chunk t&3);
  // logical k-chunk c = (t&3) ^ ((row>>1)&3)  (proven involution, r1-r8)
  const int srow = t >> 2;
  const int cOff = ((t & 3) ^ ((srow >> 1) & 3)) * 8;
  const unsigned short* aP[AUN];
  const unsigned short* bP[2];
#pragma unroll
  for (int u = 0; u < AUN; ++u)
    aP[u] = A + (size_t)(m0 + u * 128 + srow) * lda + cOff;
#pragma unroll
  for (int u = 0; u < 2; ++u)
    bP[u] = Bt + (size_t)(n0 + u * 128 + srow) * ldb + cOff;
  const int ldst = t * 16;

  // LDS read offsets (same involution): byte = r*64 + (lg^((r>>1)&3))*16
  int aoff[RM], boff[4];
#pragma unroll
  for (int f = 0; f < RM; ++f) {
    int r = wm * (BM / 2) + f * 16 + l15;
    aoff[f] = r * 64 + ((lg ^ ((r >> 1) & 3)) << 4);
  }
#pragma unroll
  for (int c = 0; c < 4; ++c) {
    int r = wn * 64 + c * 16 + l15;
    boff[c] = ABYTES + r * 64 + ((lg ^ ((r >> 1) & 3)) << 4);
  }

  f32x4 acc[RM][4];
  const f32x4 zero = {0.f, 0.f, 0.f, 0.f};
#pragma unroll
  for (int i = 0; i < RM; ++i)
#pragma unroll
    for (int j = 0; j < 4; ++j) acc[i][j] = zero;

  const int NT = K >> 5;

  // prologue: stage tiles 0 and 1; retire tile 0 (leave tile 1's U in flight)
#pragma unroll
  for (int T0 = 0; T0 < 2; ++T0) {
    char* S = lds + T0 * SLOT;
    const int k0 = T0 << 5;
#pragma unroll
    for (int u = 0; u < AUN; ++u) gload16(aP[u] + k0, S + u * 8192 + ldst);
#pragma unroll
    for (int u = 0; u < 2; ++u)
      gload16(bP[u] + k0, S + ABYTES + u * 8192 + ldst);
  }
  waitv<U>();
  __builtin_amdgcn_s_barrier();

  for (int T = 0; T < NT; ++T) {
    const char* Sb = lds + (T % 3) * SLOT;
    bf16x8 af[RM], bcr[4];
#pragma unroll
    for (int f = 0; f < RM; ++f) af[f] = ldr(Sb + aoff[f]);
#pragma unroll
    for (int c = 0; c < 4; ++c) bcr[c] = ldr(Sb + boff[c]);
    if (T + 2 < NT) {
      char* Sn = lds + ((T + 2) % 3) * SLOT;
      const int kn = (T + 2) << 5;
#pragma unroll
      for (int u = 0; u < AUN; ++u) gload16(aP[u] + kn, Sn + u * 8192 + ldst);
#pragma unroll
      for (int u = 0; u < 2; ++u)
        gload16(bP[u] + kn, Sn + ABYTES + u * 8192 + ldst);
    }
#pragma unroll
    for (int f = 0; f < RM; ++f)
#pragma unroll
      for (int c = 0; c < 4; ++c)
        acc[f][c] = __builtin_amdgcn_mfma_f32_16x16x32_bf16(
            af[f], bcr[c], acc[f][c], 0, 0, 0);
    if (T + 2 < NT) waitv<U>();
    else waitv<0>();
    __builtin_amdgcn_s_barrier();
  }

  // epilogue: D row = lg*4 + reg (within 16), col = l15 (m89-verified)
  const int rb = m0 + wm * (BM / 2) + (lg << 2);
  const int cb = n0 + wn * 64 + l15;
  if (EPI == 0) {
#pragma unroll
    for (int fg = 0; fg < RM; ++fg) {
#pragma unroll
      for (int j = 0; j < 4; ++j) {
        int col = cb + j * 16;
        float bv = bias[col];
#pragma unroll
        for (int r = 0; r < 4; ++r) {
          int row = rb + fg * 16 + r;
          float v = acc[fg][j][r] + bv;
          outb[(size_t)row * N + col] = f2bf(fmaxf(v, 0.f));
        }
      }
    }
  } else {
#pragma unroll
    for (int fg = 0; fg < RM; ++fg) {
      float gv[4];
#pragma unroll
      for (int r = 0; r < 4; ++r)
        gv[r] = gates[(size_t)(rb + fg * 16 + r) * NEXP + eidx];
#pragma unroll
      for (int j = 0; j < 4; ++j) {
        int col = cb + j * 16;
        float bv = bias[col];
#pragma unroll
        for (int r = 0; r < 4; ++r) {
          size_t o = (size_t)(rb + fg * 16 + r) * N + col;
          float v = (acc[fg][j][r] + bv) * gv[r];
          outf[o] = accum ? outf[o] + v : v;
        }
      }
    }
  }
}

// ---------------- gating head ----------------
__global__ __launch_bounds__(512)
void gating_head2(const unsigned short* __restrict__ gh,
                  const float* __restrict__ gW2,
                  const float* __restrict__ gb2,
                  float* __restrict__ gws,
                  float* __restrict__ g1,
                  float* __restrict__ g2) {
  __shared__ float wT[8][2048];
  const int t = threadIdx.x;
  for (int idx = t; idx < 16384; idx += 512) {
    wT[idx & 7][idx >> 3] = gW2[idx];
  }
  __syncthreads();
  const int wid = t >> 6, lane = t & 63;
  const int row = blockIdx.x * 8 + wid;
  const unsigned short* ghr = gh + (size_t)row * 2048;
  float s[8] = {0.f, 0.f, 0.f, 0.f, 0.f, 0.f, 0.f, 0.f};
#pragma unroll
  for (int j = 0; j < 8; ++j) {
    int k4 = lane + 64 * j;
    ushort4 hv = ((const ushort4*)ghr)[k4];
    float h0 = b2f(hv.x), h1 = b2f(hv.y), h2 = b2f(hv.z), h3 = b2f(hv.w);
#pragma unroll
    for (int e = 0; e < 8; ++e) {
      float4 w = ((const float4*)&wT[e][0])[k4];
      s[e] += h0 * w.x + h1 * w.y + h2 * w.z + h3 * w.w;
    }
  }
#pragma unroll
  for (int e = 0; e < 8; ++e)
#pragma unroll
    for (int off = 1; off < 64; off <<= 1) s[e] += __shfl_xor(s[e], off, 64);
  if (lane == 0) {
    float l[8], m = -1e30f;
#pragma unroll
    for (int e = 0; e < 8; ++e) {
      l[e] = s[e] + gb2[e];
      m = fmaxf(m, l[e]);
    }
    float sum = 0.f;
#pragma unroll
    for (int e = 0; e < 8; ++e) {
      l[e] = expf(l[e] - m);
      sum += l[e];
    }
    float inv = 1.f / sum;
#pragma unroll
    for (int e = 0; e < 8; ++e) {
      float gv = l[e] * inv;
      gws[(size_t)row * 8 + e] = gv;
      g1[(size_t)row * 8 + e] = gv;
      g2[(size_t)row * 8 + e] = gv;
    }
  }
}

extern "C" void kernel_launch(void* const* d_in, const int* in_sizes, int n_in,
                              void* d_out, int out_size, void* d_ws,
                              size_t ws_size, hipStream_t stream) {
  (void)in_sizes; (void)n_in; (void)out_size; (void)ws_size;
  const float* x   = (const float*)d_in[0];
  const float* gW1 = (const float*)d_in[1];
  const float* gb1 = (const float*)d_in[2];
  const float* gW2 = (const float*)d_in[3];
  const float* gb2 = (const float*)d_in[4];
  const float* eW1 = (const float*)d_in[5];
  const float* eb1 = (const float*)d_in[6];
  const float* eW2 = (const float*)d_in[7];
  const float* eb2 = (const float*)d_in[8];

  float* outC  = (float*)d_out;                       // [8192,1024]
  float* outG1 = outC + (size_t)BB * DOUT;            // [8192,8]
  float* outG2 = outG1 + (size_t)BB * NEXP;           // [8192,8]

  char* ws = (char*)d_ws;
  // layout: 100,925,440 B total
  unsigned short* xb   = (unsigned short*)(ws);                 // 16 MB
  float*          gat  = (float*)(ws + 16777216);               // 256 KB
  unsigned short* w1T  = (unsigned short*)(ws + 17039360);      // 8 MB
  unsigned short* w2T  = (unsigned short*)(ws + 25427968);      // 8 MB
  unsigned short* hbuf = (unsigned short*)(ws + 33816576);      // 64 MB
  unsigned short* gh   = hbuf;                  // pre-loop alias (32 MB)
  unsigned short* gW1T = w1T;                   // pre-loop alias (4 MB)

  // x -> bf16
  cvt_f32_bf16<<<(BB * DIN / 4) / 256, 256, 0, stream>>>(x, xb, BB * DIN / 4);
  // gW1 [1024][2048] -> gW1T [2048][1024] bf16
  transpose_cvt64<<<dim3(GH_N / 64, DIN / 64), 256, 0, stream>>>(gW1, gW1T, DIN, GH_N);
  // gating GEMM: gh = relu(x @ gW1 + gb1)   grid 256 (full chip)
  gemmK<256, 0><<<256, 512, 0, stream>>>(
      xb, DIN, gW1T, DIN, GH_N, DIN, gb1, gh, nullptr, nullptr, 0, 0, 256);
  gating_head2<<<BB / 8, 512, 0, stream>>>(gh, gW2, gb2, gat, outG1, outG2);

  for (int e = 0; e < NEXP; ++e) {
    transpose_cvt2<<<2048, 256, 0, stream>>>(
        eW1 + (size_t)e * DIN * DHID, w1T, eW2 + (size_t)e * DHID * DOUT, w2T);
    // G1: h = relu(x @ eW1_e + eb1_e)   grid 512 (2 exact rounds)
    gemmK<256, 0><<<512, 512, 0, stream>>>(
        xb, DIN, w1T, DIN, DHID, DIN, eb1 + (size_t)e * DHID,
        hbuf, nullptr, nullptr, 0, 0, 512);
    // G2: outC (+)= gat[:,e]*(h @ eW2_e + eb2_e)   grid 256 (full chip, 2/CU)
    gemmK<128, 1><<<256, 512, 0, stream>>>(
        hbuf, DHID, w2T, DHID, DOUT, DHID, eb2 + (size_t)e * DOUT,
        nullptr, outC, gat, e, e > 0 ? 1 : 0, 256);
  }
}

// Round 10
// 1346.115 us; speedup vs baseline: 1.0254x; 1.0254x over previous
//
#include <hip/hip_runtime.h>
#include <hip/hip_bf16.h>
#include <stdint.h>

// B=8192, D_IN=1024, D_HID=4096, D_OUT=1024, E=8
#define BB 8192
#define DIN 1024
#define DHID 4096
#define DOUT 1024
#define NEXP 8
#define GH_N 2048  // D_HID/2

typedef __attribute__((ext_vector_type(8))) __bf16 bf16x8;
typedef __attribute__((ext_vector_type(4))) float f32x4;

__device__ inline unsigned short f2bf(float f) {
  unsigned u = __builtin_bit_cast(unsigned, f);
  u = (u + 0x7FFFu + ((u >> 16) & 1u)) >> 16;
  return (unsigned short)u;
}
__device__ inline float b2f(unsigned short s) {
  return __builtin_bit_cast(float, (unsigned)s << 16);
}

// ---------------- elementwise f32 -> bf16 ----------------
__global__ void cvt_f32_bf16(const float* __restrict__ in,
                             unsigned short* __restrict__ out, int n4) {
  int i = blockIdx.x * blockDim.x + threadIdx.x;
  if (i >= n4) return;
  float4 v = ((const float4*)in)[i];
  ushort4 o;
  o.x = f2bf(v.x); o.y = f2bf(v.y); o.z = f2bf(v.z); o.w = f2bf(v.w);
  ((ushort4*)out)[i] = o;
}

// ---- 64x64 transpose tile, 512 threads, caller-provided LDS ----
__device__ inline void tr64(float (*tile)[65], const float* __restrict__ in,
                            unsigned short* __restrict__ out, int R, int C,
                            int bx, int by, int t) {
  const int c0 = bx * 64, r0 = by * 64;
  const int tx = t & 63, ty = t >> 6;  // ty 0..7
#pragma unroll
  for (int i = 0; i < 8; ++i) {
    int r = i * 8 + ty;
    tile[r][tx] = in[(size_t)(r0 + r) * C + c0 + tx];
  }
  __syncthreads();
#pragma unroll
  for (int i = 0; i < 8; ++i) {
    int r = i * 8 + ty;
    out[(size_t)(c0 + r) * R + r0 + tx] = f2bf(tile[tx][r]);
  }
  __syncthreads();
}

// pre-loop transposes: gW1 [1024][2048]->gW1T, eW1_0 -> w1A, eW2_0 -> w2A
__global__ __launch_bounds__(512)
void trans_pre(const float* __restrict__ gW1, unsigned short* __restrict__ gW1T,
               const float* __restrict__ w1, unsigned short* __restrict__ w1T,
               const float* __restrict__ w2, unsigned short* __restrict__ w2T) {
  __shared__ float tile[64][65];
  int b = blockIdx.x;
  if (b < 512) {
    tr64(tile, gW1, gW1T, DIN, GH_N, b & 31, b >> 5, threadIdx.x);
  } else if (b < 1536) {
    b -= 512;
    tr64(tile, w1, w1T, DIN, DHID, b & 63, b >> 6, threadIdx.x);
  } else {
    b -= 1536;
    tr64(tile, w2, w2T, DHID, DOUT, b & 15, b >> 4, threadIdx.x);
  }
}

// ---------------- async global->LDS 16B ----------------
__device__ inline void gload16(const void* g, void* l) {
  __builtin_amdgcn_global_load_lds(
      (const __attribute__((address_space(1))) void*)g,
      (__attribute__((address_space(3))) void*)l, 16, 0, 0);
}

template <int N>
__device__ inline void waitv() {
  if constexpr (N == 0) asm volatile("s_waitcnt vmcnt(0)" ::: "memory");
  else if constexpr (N == 2) asm volatile("s_waitcnt vmcnt(2)" ::: "memory");
  else if constexpr (N == 4) asm volatile("s_waitcnt vmcnt(4)" ::: "memory");
  else if constexpr (N == 6) asm volatile("s_waitcnt vmcnt(6)" ::: "memory");
  else asm volatile("s_waitcnt vmcnt(0)" ::: "memory");
}
__device__ inline void waitlgkm0() {
  asm volatile("s_waitcnt lgkmcnt(0)" ::: "memory");
  __builtin_amdgcn_sched_barrier(0);
}
__device__ inline bf16x8 ldr(const char* p) { return *(const bf16x8*)p; }

// ---------------- gemmU: 256x256 fat 4-phase (proven ~1270 TF) -------------
// C = A[8192,K]*Bt[N,K]^T, epi: outb = bf16(relu(acc+bias[col]))
struct GArgs {
  const unsigned short* A;
  const unsigned short* Bt;
  int lda, ldb, N, K;
  const float* bias;
  unsigned short* outb;
  int nb;
};

__global__ __launch_bounds__(512, 2)
void gemmU(GArgs g) {
  __shared__ char lds[131072];
  char* Als = lds;
  char* Bls = lds + 65536;
  constexpr int ABYTES = 32768, BBYTES = 32768;
  const int t = threadIdx.x;
  const int lane = t & 63;
  const int wid = t >> 6;
  const int wm = wid >> 2;
  const int wn = wid & 3;
  const int l15 = lane & 15, lg = lane >> 4;

  const int nb = g.nb;
  const int local = blockIdx.x;
  const int swz = (local & 7) * (nb >> 3) + (local >> 3);
  const int nbn = g.N >> 8;
  const int bn = swz % nbn, bm = swz / nbn;
  const int m0 = bm * 256, n0 = bn * 256;

  const int prow = t >> 3;
  const int cOff = ((t & 7) ^ (prow & 7)) * 8;
  const unsigned short* aP[4];
  const unsigned short* bP[4];
#pragma unroll
  for (int u = 0; u < 4; ++u) {
    int p = u * 64 + prow;
    int ga = ((p >> 6) & 1) * 128 + ((p >> 7) & 1) * 64 + (p & 63);
    aP[u] = g.A + (size_t)(m0 + ga) * g.lda + cOff;
    int gb = ((p >> 5) & 3) * 64 + ((p >> 7) & 1) * 32 + (p & 31);
    bP[u] = g.Bt + (size_t)(n0 + gb) * g.ldb + cOff;
  }
  const int ldst = t * 16;

  const int slot0 = ((lg) ^ (l15 & 7)) * 16;
  const int slot1 = ((4 + lg) ^ (l15 & 7)) * 16;
  const int aRB0 = (wm * 64 + l15) * 128;
  const int aRB1 = (128 + wm * 64 + l15) * 128;
  const int bCB0 = (wn * 32 + l15) * 128;
  const int bCB1 = (128 + wn * 32 + l15) * 128;

  f32x4 acc[8][4];
  const f32x4 zero = {0.f, 0.f, 0.f, 0.f};
#pragma unroll
  for (int i = 0; i < 8; ++i)
#pragma unroll
    for (int j = 0; j < 4; ++j) acc[i][j] = zero;

  bf16x8 ar[4][2], bc0[2][2], bc1[2][2];
  const int NT = g.K >> 6;

  gload16(bP[0], Bls + 0 * 8192 + ldst);
  gload16(bP[1], Bls + 1 * 8192 + ldst);
  gload16(aP[0], Als + 0 * 8192 + ldst);
  gload16(aP[1], Als + 1 * 8192 + ldst);
  gload16(bP[2], Bls + 2 * 8192 + ldst);
  gload16(bP[3], Bls + 3 * 8192 + ldst);
  gload16(aP[2], Als + 2 * 8192 + ldst);
  gload16(aP[3], Als + 3 * 8192 + ldst);
  waitv<4>();
  __builtin_amdgcn_s_barrier();

  for (int T = 0; T < NT; ++T) {
    const int buf = T & 1;
    const char* Ab = Als + buf * ABYTES;
    const char* Bb = Bls + buf * BBYTES;
    char* An = Als + (buf ^ 1) * ABYTES;
    char* Bn = Bls + (buf ^ 1) * BBYTES;
    const bool stg = (T + 1 < NT);
    const int kn = (T + 1) << 6;

    // ph0
#pragma unroll
    for (int f = 0; f < 4; ++f) {
      ar[f][0] = ldr(Ab + aRB0 + f * 2048 + slot0);
      ar[f][1] = ldr(Ab + aRB0 + f * 2048 + slot1);
    }
#pragma unroll
    for (int c = 0; c < 2; ++c) {
      bc0[c][0] = ldr(Bb + bCB0 + c * 2048 + slot0);
      bc0[c][1] = ldr(Bb + bCB0 + c * 2048 + slot1);
    }
    if (stg) {
      gload16(bP[0] + kn, Bn + 0 * 8192 + ldst);
      gload16(bP[1] + kn, Bn + 1 * 8192 + ldst);
    }
    __builtin_amdgcn_s_barrier();
    waitlgkm0();
    __builtin_amdgcn_s_setprio(1);
#pragma unroll
    for (int ksl = 0; ksl < 2; ++ksl)
#pragma unroll
      for (int f = 0; f < 4; ++f)
#pragma unroll
        for (int c = 0; c < 2; ++c)
          acc[f][c] = __builtin_amdgcn_mfma_f32_16x16x32_bf16(
              ar[f][ksl], bc0[c][ksl], acc[f][c], 0, 0, 0);
    __builtin_amdgcn_s_setprio(0);
    if (stg) waitv<4>(); else waitv<2>();
    __builtin_amdgcn_s_barrier();

    // ph1
#pragma unroll
    for (int c = 0; c < 2; ++c) {
      bc1[c][0] = ldr(Bb + bCB1 + c * 2048 + slot0);
      bc1[c][1] = ldr(Bb + bCB1 + c * 2048 + slot1);
    }
    if (stg) {
      gload16(aP[0] + kn, An + 0 * 8192 + ldst);
      gload16(aP[1] + kn, An + 1 * 8192 + ldst);
    }
    __builtin_amdgcn_s_barrier();
    waitlgkm0();
    __builtin_amdgcn_s_setprio(1);
#pragma unroll
    for (int ksl = 0; ksl < 2; ++ksl)
#pragma unroll
      for (int f = 0; f < 4; ++f)
#pragma unroll
        for (int c = 0; c < 2; ++c)
          acc[f][2 + c] = __builtin_amdgcn_mfma_f32_16x16x32_bf16(
              ar[f][ksl], bc1[c][ksl], acc[f][2 + c], 0, 0, 0);
    __builtin_amdgcn_s_setprio(0);
    if (stg) waitv<4>(); else waitv<0>();
    __builtin_amdgcn_s_barrier();

    // ph2
#pragma unroll
    for (int f = 0; f < 4; ++f) {
      ar[f][0] = ldr(Ab + aRB1 + f * 2048 + slot0);
      ar[f][1] = ldr(Ab + aRB1 + f * 2048 + slot1);
    }
    if (stg) {
      gload16(bP[2] + kn, Bn + 2 * 8192 + ldst);
      gload16(bP[3] + kn, Bn + 3 * 8192 + ldst);
    }
    __builtin_amdgcn_s_barrier();
    waitlgkm0();
    __builtin_amdgcn_s_setprio(1);
#pragma unroll
    for (int ksl = 0; ksl < 2; ++ksl)
#pragma unroll
      for (int f = 0; f < 4; ++f)
#pragma unroll
        for (int c = 0; c < 2; ++c)
          acc[4 + f][2 + c] = __builtin_amdgcn_mfma_f32_16x16x32_bf16(
              ar[f][ksl], bc1[c][ksl], acc[4 + f][2 + c], 0, 0, 0);
    __builtin_amdgcn_s_setprio(0);
    __builtin_amdgcn_s_barrier();

    // ph3
    if (stg) {
      gload16(aP[2] + kn, An + 2 * 8192 + ldst);
      gload16(aP[3] + kn, An + 3 * 8192 + ldst);
    }
    __builtin_amdgcn_s_barrier();
    __builtin_amdgcn_s_setprio(1);
#pragma unroll
    for (int ksl = 0; ksl < 2; ++ksl)
#pragma unroll
      for (int f = 0; f < 4; ++f)
#pragma unroll
        for (int c = 0; c < 2; ++c)
          acc[4 + f][c] = __builtin_amdgcn_mfma_f32_16x16x32_bf16(
              ar[f][ksl], bc0[c][ksl], acc[4 + f][c], 0, 0, 0);
    __builtin_amdgcn_s_setprio(0);
    if (stg) waitv<4>();
    __builtin_amdgcn_s_barrier();
  }

  const int rb = m0 + wm * 128 + (lg << 2);
  const int cb = n0 + wn * 64 + l15;
  const int N = g.N;
#pragma unroll
  for (int fg = 0; fg < 8; ++fg) {
#pragma unroll
    for (int j = 0; j < 4; ++j) {
      int col = cb + j * 16;
      float bv = g.bias[col];
#pragma unroll
      for (int r = 0; r < 4; ++r) {
        int row = rb + fg * 16 + r;
        float v = acc[fg][j][r] + bv;
        g.outb[(size_t)row * N + col] = f2bf(fmaxf(v, 0.f));
      }
    }
  }
}

// ---------------- gemmF core: 128x256, 2 fat phases, 3-buf ring ------------
__device__ __forceinline__
void gemmF_core(char* lds,
                const unsigned short* __restrict__ A,
                const unsigned short* __restrict__ Bt,
                const float* __restrict__ bias,
                float* __restrict__ outC,
                const float* __restrict__ gates, int eidx, int accum) {
  constexpr int SLOT = 49152;  // 16KB A + 32KB B
  const int t = threadIdx.x;
  const int lane = t & 63;
  const int wid = t >> 6;
  const int wm = wid >> 2;  // 0..1
  const int wn = wid & 3;   // 0..3
  const int l15 = lane & 15, lg = lane >> 4;

  const int local = blockIdx.x;
  const int swz = (local & 7) * 32 + (local >> 3);
  const int bn = swz & 3, bm = swz >> 2;
  const int m0 = bm * 128, n0 = bn * 256;

  const int prow = t >> 3;
  const int cOff = ((t & 7) ^ (prow & 7)) * 8;
  const unsigned short* aP[2];
  const unsigned short* bP[4];
#pragma unroll
  for (int u = 0; u < 2; ++u)
    aP[u] = A + (size_t)(m0 + u * 64 + prow) * DHID + cOff;
#pragma unroll
  for (int u = 0; u < 4; ++u) {
    int p = u * 64 + prow;
    int gb = ((p >> 5) & 3) * 64 + ((p >> 7) & 1) * 32 + (p & 31);
    bP[u] = Bt + (size_t)(n0 + gb) * DHID + cOff;
  }
  const int ldst = t * 16;

  const int slot0 = ((lg) ^ (l15 & 7)) * 16;
  const int slot1 = ((4 + lg) ^ (l15 & 7)) * 16;
  const int aRB = (wm * 64 + l15) * 128;
  const int bCB0 = 16384 + (wn * 32 + l15) * 128;
  const int bCB1 = 16384 + (128 + wn * 32 + l15) * 128;

  f32x4 acc[4][4];
  const f32x4 zero = {0.f, 0.f, 0.f, 0.f};
#pragma unroll
  for (int i = 0; i < 4; ++i)
#pragma unroll
    for (int j = 0; j < 4; ++j) acc[i][j] = zero;

  bf16x8 af[2][2], bc[4][2];
  const int NT = DHID >> 6;  // 64

#pragma unroll
  for (int T0 = 0; T0 < 2; ++T0) {
    char* S = lds + T0 * SLOT;
    const int k0 = T0 << 6;
    gload16(aP[0] + k0, S + 0 * 8192 + ldst);
    gload16(aP[1] + k0, S + 1 * 8192 + ldst);
    gload16(bP[0] + k0, S + 16384 + 0 * 8192 + ldst);
    gload16(bP[1] + k0, S + 16384 + 1 * 8192 + ldst);
    gload16(bP[2] + k0, S + 16384 + 2 * 8192 + ldst);
    gload16(bP[3] + k0, S + 16384 + 3 * 8192 + ldst);
  }
  waitv<6>();
  __builtin_amdgcn_s_barrier();

  for (int T = 0; T < NT; ++T) {
    const char* Sb = lds + (T % 3) * SLOT;
    char* Sn = lds + ((T + 2) % 3) * SLOT;
    const bool stg = (T + 2 < NT);
    const int kn = (T + 2) << 6;

    // ph0
#pragma unroll
    for (int f = 0; f < 2; ++f) {
      af[f][0] = ldr(Sb + aRB + f * 2048 + slot0);
      af[f][1] = ldr(Sb + aRB + f * 2048 + slot1);
    }
#pragma unroll
    for (int c = 0; c < 2; ++c) {
      bc[c][0] = ldr(Sb + bCB0 + c * 2048 + slot0);
      bc[c][1] = ldr(Sb + bCB0 + c * 2048 + slot1);
      bc[2 + c][0] = ldr(Sb + bCB1 + c * 2048 + slot0);
      bc[2 + c][1] = ldr(Sb + bCB1 + c * 2048 + slot1);
    }
    if (stg) {
      gload16(aP[0] + kn, Sn + 0 * 8192 + ldst);
      gload16(aP[1] + kn, Sn + 1 * 8192 + ldst);
      gload16(bP[0] + kn, Sn + 16384 + 0 * 8192 + ldst);
    }
    __builtin_amdgcn_s_barrier();
    waitlgkm0();
    __builtin_amdgcn_s_setprio(1);
#pragma unroll
    for (int ksl = 0; ksl < 2; ++ksl)
#pragma unroll
      for (int f = 0; f < 2; ++f)
#pragma unroll
        for (int c = 0; c < 4; ++c)
          acc[f][c] = __builtin_amdgcn_mfma_f32_16x16x32_bf16(
              af[f][ksl], bc[c][ksl], acc[f][c], 0, 0, 0);
    __builtin_amdgcn_s_setprio(0);
    __builtin_amdgcn_s_barrier();

    // ph1
#pragma unroll
    for (int f = 0; f < 2; ++f) {
      af[f][0] = ldr(Sb + aRB + (2 + f) * 2048 + slot0);
      af[f][1] = ldr(Sb + aRB + (2 + f) * 2048 + slot1);
    }
    if (stg) {
      gload16(bP[1] + kn, Sn + 16384 + 1 * 8192 + ldst);
      gload16(bP[2] + kn, Sn + 16384 + 2 * 8192 + ldst);
      gload16(bP[3] + kn, Sn + 16384 + 3 * 8192 + ldst);
    }
    __builtin_amdgcn_s_barrier();
    waitlgkm0();
    __builtin_amdgcn_s_setprio(1);
#pragma unroll
    for (int ksl = 0; ksl < 2; ++ksl)
#pragma unroll
      for (int f = 0; f < 2; ++f)
#pragma unroll
        for (int c = 0; c < 4; ++c)
          acc[2 + f][c] = __builtin_amdgcn_mfma_f32_16x16x32_bf16(
              af[f][ksl], bc[c][ksl], acc[2 + f][c], 0, 0, 0);
    __builtin_amdgcn_s_setprio(0);
    if (stg) waitv<6>();
    else if (T + 1 < NT) waitv<0>();
    __builtin_amdgcn_s_barrier();
  }

  const int rb = m0 + wm * 64 + (lg << 2);
  const int cb = n0 + wn * 64 + l15;
#pragma unroll
  for (int fg = 0; fg < 4; ++fg) {
    float gv[4];
#pragma unroll
    for (int r = 0; r < 4; ++r)
      gv[r] = gates[(size_t)(rb + fg * 16 + r) * NEXP + eidx];
#pragma unroll
    for (int j = 0; j < 4; ++j) {
      int col = cb + j * 16;
      float bv = bias[col];
#pragma unroll
      for (int r = 0; r < 4; ++r) {
        size_t o = (size_t)(rb + fg * 16 + r) * DOUT + col;
        float v = (acc[fg][j][r] + bv) * gv[r];
        outC[o] = accum ? outC[o] + v : v;
      }
    }
  }
}

// ---- fused dispatch: blocks [0,256) = gemmF(G2,e); [256,512) = transposes
// of expert e+1 weights into the ping-pong buffers (8 tiles/block).
__global__ __launch_bounds__(512)
void g2t(const unsigned short* __restrict__ A,
         const unsigned short* __restrict__ Bt,
         const float* __restrict__ bias,
         float* __restrict__ outC,
         const float* __restrict__ gates, int eidx, int accum,
         const float* __restrict__ nw1, unsigned short* __restrict__ nw1T,
         const float* __restrict__ nw2, unsigned short* __restrict__ nw2T) {
  __shared__ char lds[147456];
  if ((int)blockIdx.x < 256) {
    gemmF_core(lds, A, Bt, bias, outC, gates, eidx, accum);
  } else {
    float(*tile)[65] = (float(*)[65])lds;
    const int tb = (int)blockIdx.x - 256;
#pragma unroll
    for (int i = 0; i < 8; ++i) {
      int ti = tb * 8 + i;
      if (ti < 1024) {
        tr64(tile, nw1, nw1T, DIN, DHID, ti & 63, ti >> 6, threadIdx.x);
      } else {
        ti -= 1024;
        tr64(tile, nw2, nw2T, DHID, DOUT, ti & 15, ti >> 4, threadIdx.x);
      }
    }
  }
}

// ---------------- gating head ----------------
__global__ __launch_bounds__(512)
void gating_head2(const unsigned short* __restrict__ gh,
                  const float* __restrict__ gW2,
                  const float* __restrict__ gb2,
                  float* __restrict__ gws,
                  float* __restrict__ g1,
                  float* __restrict__ g2) {
  __shared__ float wT[8][2048];
  const int t = threadIdx.x;
  for (int idx = t; idx < 16384; idx += 512) {
    wT[idx & 7][idx >> 3] = gW2[idx];
  }
  __syncthreads();
  const int wid = t >> 6, lane = t & 63;
  const int row = blockIdx.x * 8 + wid;
  const unsigned short* ghr = gh + (size_t)row * 2048;
  float s[8] = {0.f, 0.f, 0.f, 0.f, 0.f, 0.f, 0.f, 0.f};
#pragma unroll
  for (int j = 0; j < 8; ++j) {
    int k4 = lane + 64 * j;
    ushort4 hv = ((const ushort4*)ghr)[k4];
    float h0 = b2f(hv.x), h1 = b2f(hv.y), h2 = b2f(hv.z), h3 = b2f(hv.w);
#pragma unroll
    for (int e = 0; e < 8; ++e) {
      float4 w = ((const float4*)&wT[e][0])[k4];
      s[e] += h0 * w.x + h1 * w.y + h2 * w.z + h3 * w.w;
    }
  }
#pragma unroll
  for (int e = 0; e < 8; ++e)
#pragma unroll
    for (int off = 1; off < 64; off <<= 1) s[e] += __shfl_xor(s[e], off, 64);
  if (lane == 0) {
    float l[8], m = -1e30f;
#pragma unroll
    for (int e = 0; e < 8; ++e) {
      l[e] = s[e] + gb2[e];
      m = fmaxf(m, l[e]);
    }
    float sum = 0.f;
#pragma unroll
    for (int e = 0; e < 8; ++e) {
      l[e] = expf(l[e] - m);
      sum += l[e];
    }
    float inv = 1.f / sum;
#pragma unroll
    for (int e = 0; e < 8; ++e) {
      float gv = l[e] * inv;
      gws[(size_t)row * 8 + e] = gv;
      g1[(size_t)row * 8 + e] = gv;
      g2[(size_t)row * 8 + e] = gv;
    }
  }
}

extern "C" void kernel_launch(void* const* d_in, const int* in_sizes, int n_in,
                              void* d_out, int out_size, void* d_ws,
                              size_t ws_size, hipStream_t stream) {
  (void)in_sizes; (void)n_in; (void)out_size; (void)ws_size;
  const float* x   = (const float*)d_in[0];
  const float* gW1 = (const float*)d_in[1];
  const float* gb1 = (const float*)d_in[2];
  const float* gW2 = (const float*)d_in[3];
  const float* gb2 = (const float*)d_in[4];
  const float* eW1 = (const float*)d_in[5];
  const float* eb1 = (const float*)d_in[6];
  const float* eW2 = (const float*)d_in[7];
  const float* eb2 = (const float*)d_in[8];

  float* outC  = (float*)d_out;                       // [8192,1024]
  float* outG1 = outC + (size_t)BB * DOUT;            // [8192,8]
  float* outG2 = outG1 + (size_t)BB * NEXP;           // [8192,8]

  char* ws = (char*)d_ws;
  // layout (117,702,656 B total; capacity >= 168,034,304 proven in r5/r6):
  unsigned short* xb   = (unsigned short*)(ws);                 // 16 MB
  float*          gat  = (float*)(ws + 16777216);               // 256 KB
  unsigned short* w1A  = (unsigned short*)(ws + 17039360);      // 8 MB
  unsigned short* w1B  = (unsigned short*)(ws + 25427968);      // 8 MB
  unsigned short* w2A  = (unsigned short*)(ws + 33816576);      // 8 MB
  unsigned short* w2B  = (unsigned short*)(ws + 42205184);      // 8 MB
  unsigned short* hbuf = (unsigned short*)(ws + 50593792);      // 64 MB
  unsigned short* gh   = hbuf;                                  // 32 MB alias
  unsigned short* gW1T = (unsigned short*)(ws + 50593792 + 33554432);  // 4 MB alias (hbuf upper half)

  // x -> bf16
  cvt_f32_bf16<<<(BB * DIN / 4) / 256, 256, 0, stream>>>(x, xb, BB * DIN / 4);
  // pre-loop transposes: gW1T (512 tiles) + expert-0 w1A/w2A (2048 tiles)
  trans_pre<<<2560, 512, 0, stream>>>(gW1, gW1T, eW1, w1A, eW2, w2A);
  // gating GEMM: gh = relu(x @ gW1 + gb1)   grid 256
  {
    GArgs a{xb, gW1T, DIN, DIN, GH_N, DIN, gb1, gh, 256};
    gemmU<<<256, 512, 0, stream>>>(a);
  }
  gating_head2<<<BB / 8, 512, 0, stream>>>(gh, gW2, gb2, gat, outG1, outG2);

  for (int e = 0; e < NEXP; ++e) {
    unsigned short* w1cur = (e & 1) ? w1B : w1A;
    unsigned short* w2cur = (e & 1) ? w2B : w2A;
    unsigned short* w1nxt = (e & 1) ? w1A : w1B;
    unsigned short* w2nxt = (e & 1) ? w2A : w2B;
    // G1: h = relu(x @ eW1_e + eb1_e)   grid 512 (2 rounds)
    {
      GArgs a{xb, w1cur, DIN, DIN, DHID, DIN, eb1 + (size_t)e * DHID, hbuf, 512};
      gemmU<<<512, 512, 0, stream>>>(a);
    }
    // G2 (+ next expert's weight transposes in the drain tail)
    if (e + 1 < NEXP) {
      g2t<<<512, 512, 0, stream>>>(
          hbuf, w2cur, eb2 + (size_t)e * DOUT, outC, gat, e, e > 0 ? 1 : 0,
          eW1 + (size_t)(e + 1) * DIN * DHID, w1nxt,
          eW2 + (size_t)(e + 1) * DHID * DOUT, w2nxt);
    } else {
      g2t<<<256, 512, 0, stream>>>(
          hbuf, w2cur, eb2 + (size_t)e * DOUT, outC, gat, e, 1,
          nullptr, nullptr, nullptr, nullptr);
    }
  }
}